// Round 1
// baseline (108.008 us; speedup 1.0000x reference)
//
#include <hip/hip_runtime.h>

#define NN      4096   // total nodes
#define BG      64     // graphs
#define NPG_    64     // nodes per graph
#define LT_     128
#define LL_     32
#define D_      256
#define OUT_    1024
#define NPB     8      // nodes per block (kernel 1)

__global__ __launch_bounds__(256) void node_kernel(
    const int*   __restrict__ text_ids,
    const int*   __restrict__ label_ids,
    const int*   __restrict__ text_len,
    const int*   __restrict__ label_len,
    const float* __restrict__ word_emb,
    const float* __restrict__ label_emb,
    const float* __restrict__ Wg_text,
    const float* __restrict__ Wg_label,
    const float* __restrict__ w_adap,
    float*       __restrict__ h_comb)    // [NN, D]
{
    __shared__ float ldsT[NPB][D_];
    __shared__ float ldsL[NPB][D_];

    const int tid  = threadIdx.x;
    const int wave = tid >> 6;
    const int lane = tid & 63;
    const int base_node = blockIdx.x * NPB;

    // ---- Phase 1: ragged gathers (each wave handles 2 nodes) ----
    for (int nd = wave; nd < NPB; nd += 4) {
        const int gn = base_node + nd;

        // text: masked mean of word_emb rows
        {
            const int len = text_len[gn];
            const int* __restrict__ ids = text_ids + (size_t)gn * LT_;
            const float* __restrict__ basep = word_emb + (size_t)lane * 4;
            float4 acc = make_float4(0.f, 0.f, 0.f, 0.f);
            #pragma unroll 4
            for (int l = 0; l < len; ++l) {
                const float4 v = *reinterpret_cast<const float4*>(
                    basep + (size_t)ids[l] * D_);
                acc.x += v.x; acc.y += v.y; acc.z += v.z; acc.w += v.w;
            }
            const float inv = 1.0f / (float)len;
            float4 r = make_float4(acc.x*inv, acc.y*inv, acc.z*inv, acc.w*inv);
            *reinterpret_cast<float4*>(&ldsT[nd][lane * 4]) = r;
        }

        // label: masked sum of label_emb rows
        {
            const int len = label_len[gn];
            const int* __restrict__ ids = label_ids + (size_t)gn * LL_;
            const float* __restrict__ basep = label_emb + (size_t)lane * 4;
            float4 acc = make_float4(0.f, 0.f, 0.f, 0.f);
            #pragma unroll 4
            for (int l = 0; l < len; ++l) {
                const float4 v = *reinterpret_cast<const float4*>(
                    basep + (size_t)ids[l] * D_);
                acc.x += v.x; acc.y += v.y; acc.z += v.z; acc.w += v.w;
            }
            *reinterpret_cast<float4*>(&ldsL[nd][lane * 4]) = acc;
        }
    }
    __syncthreads();

    // ---- Phase 2: batched matvec for both projections (8 nodes reuse Wg) ----
    const int j = tid;   // output column
    float accT[NPB], accL[NPB];
    #pragma unroll
    for (int nd = 0; nd < NPB; ++nd) { accT[nd] = 0.f; accL[nd] = 0.f; }

    for (int d4 = 0; d4 < D_; d4 += 4) {
        const float wt0 = Wg_text[(size_t)(d4+0)*D_ + j];
        const float wt1 = Wg_text[(size_t)(d4+1)*D_ + j];
        const float wt2 = Wg_text[(size_t)(d4+2)*D_ + j];
        const float wt3 = Wg_text[(size_t)(d4+3)*D_ + j];
        const float wl0 = Wg_label[(size_t)(d4+0)*D_ + j];
        const float wl1 = Wg_label[(size_t)(d4+1)*D_ + j];
        const float wl2 = Wg_label[(size_t)(d4+2)*D_ + j];
        const float wl3 = Wg_label[(size_t)(d4+3)*D_ + j];
        #pragma unroll
        for (int nd = 0; nd < NPB; ++nd) {
            const float4 t = *reinterpret_cast<const float4*>(&ldsT[nd][d4]);
            accT[nd] = fmaf(t.w, wt3, fmaf(t.z, wt2, fmaf(t.y, wt1, fmaf(t.x, wt0, accT[nd]))));
            const float4 lv = *reinterpret_cast<const float4*>(&ldsL[nd][d4]);
            accL[nd] = fmaf(lv.w, wl3, fmaf(lv.z, wl2, fmaf(lv.y, wl1, fmaf(lv.x, wl0, accL[nd]))));
        }
    }

    const float w0 = w_adap[0] * (1.0f / (float)NPG_);
    const float w1 = w_adap[1] * (1.0f / (float)NPG_);
    #pragma unroll
    for (int nd = 0; nd < NPB; ++nd) {
        const float ht = accT[nd] > 0.f ? accT[nd] : 0.f;
        const float hl = accL[nd] > 0.f ? accL[nd] : 0.f;
        h_comb[(size_t)(base_node + nd) * D_ + j] = w0 * ht + w1 * hl;
    }
}

__global__ __launch_bounds__(256) void graph_kernel(
    const float* __restrict__ h_comb,   // [NN, D]
    const float* __restrict__ W1,       // [D, D]
    const float* __restrict__ b1,       // [D]
    const float* __restrict__ Wout,     // [D, OUT]
    const float* __restrict__ bout,     // [OUT]
    float*       __restrict__ out)      // [BG, OUT]
{
    __shared__ float fused[D_];
    __shared__ float hrow[D_];

    const int b   = blockIdx.x;
    const int tid = threadIdx.x;

    // segment sum over the 64 nodes of this graph (scaling already applied)
    float acc = 0.f;
    const float* __restrict__ basep = h_comb + (size_t)b * NPG_ * D_ + tid;
    #pragma unroll 8
    for (int n = 0; n < NPG_; ++n) acc += basep[(size_t)n * D_];
    fused[tid] = acc;
    __syncthreads();

    // h = relu(fused @ W1 + b1)
    float a1 = b1[tid];
    for (int d = 0; d < D_; ++d)
        a1 = fmaf(fused[d], W1[(size_t)d * D_ + tid], a1);
    hrow[tid] = a1 > 0.f ? a1 : 0.f;
    __syncthreads();

    // out = h @ Wout + bout   (each thread owns 4 output columns)
    float o0 = bout[tid +   0];
    float o1 = bout[tid + 256];
    float o2 = bout[tid + 512];
    float o3 = bout[tid + 768];
    for (int d = 0; d < D_; ++d) {
        const float hv = hrow[d];
        const float* __restrict__ wrow = Wout + (size_t)d * OUT_ + tid;
        o0 = fmaf(hv, wrow[  0], o0);
        o1 = fmaf(hv, wrow[256], o1);
        o2 = fmaf(hv, wrow[512], o2);
        o3 = fmaf(hv, wrow[768], o3);
    }
    float* __restrict__ op = out + (size_t)b * OUT_ + tid;
    op[  0] = o0;
    op[256] = o1;
    op[512] = o2;
    op[768] = o3;
}

extern "C" void kernel_launch(void* const* d_in, const int* in_sizes, int n_in,
                              void* d_out, int out_size, void* d_ws, size_t ws_size,
                              hipStream_t stream) {
    const int*   text_ids  = (const int*)  d_in[0];
    const int*   label_ids = (const int*)  d_in[1];
    const int*   text_len  = (const int*)  d_in[2];
    const int*   label_len = (const int*)  d_in[3];
    const float* word_emb  = (const float*)d_in[4];
    const float* label_emb = (const float*)d_in[5];
    const float* Wg_text   = (const float*)d_in[6];
    const float* Wg_label  = (const float*)d_in[7];
    const float* w_adap    = (const float*)d_in[8];
    const float* W1        = (const float*)d_in[9];
    const float* b1        = (const float*)d_in[10];
    const float* Wout      = (const float*)d_in[11];
    const float* bout      = (const float*)d_in[12];

    float* h_comb = (float*)d_ws;          // NN * D * 4 = 4 MiB scratch
    float* out    = (float*)d_out;         // [BG, OUT] f32

    node_kernel<<<NN / NPB, 256, 0, stream>>>(
        text_ids, label_ids, text_len, label_len,
        word_emb, label_emb, Wg_text, Wg_label, w_adap, h_comb);

    graph_kernel<<<BG, 256, 0, stream>>>(
        h_comb, W1, b1, Wout, bout, out);
}

// Round 2
// 102.354 us; speedup vs baseline: 1.0552x; 1.0552x over previous
//
#include <hip/hip_runtime.h>

#define NN      4096   // total nodes
#define BG      64     // graphs
#define NPG_    64     // nodes per graph
#define LT_     128
#define LL_     32
#define D_      256
#define OUT_    1024
#define NPB     8      // nodes per block (proj kernel)

// ---------------- Kernel A: ragged gathers, 1 node per block, 4 waves split the bag ----------------
__global__ __launch_bounds__(256) void gather_kernel(
    const int*   __restrict__ text_ids,
    const int*   __restrict__ label_ids,
    const int*   __restrict__ text_len,
    const int*   __restrict__ label_len,
    const float* __restrict__ word_emb,
    const float* __restrict__ label_emb,
    float*       __restrict__ text_out,   // [NN, D]
    float*       __restrict__ label_out)  // [NN, D]
{
    __shared__ float ldsT[4][D_];
    __shared__ float ldsL[4][D_];

    const int n    = blockIdx.x;
    const int tid  = threadIdx.x;
    const int wave = tid >> 6;
    const int lane = tid & 63;

    // text partial sum: wave w takes l = w, w+4, ...
    {
        const int len = text_len[n];
        const int* __restrict__ ids = text_ids + (size_t)n * LT_;
        const float* __restrict__ basep = word_emb + (size_t)lane * 4;
        float4 acc = make_float4(0.f, 0.f, 0.f, 0.f);
        #pragma unroll 4
        for (int l = wave; l < len; l += 4) {
            const float4 v = *reinterpret_cast<const float4*>(
                basep + (size_t)ids[l] * D_);
            acc.x += v.x; acc.y += v.y; acc.z += v.z; acc.w += v.w;
        }
        *reinterpret_cast<float4*>(&ldsT[wave][lane * 4]) = acc;
    }

    // label partial sum
    {
        const int len = label_len[n];
        const int* __restrict__ ids = label_ids + (size_t)n * LL_;
        const float* __restrict__ basep = label_emb + (size_t)lane * 4;
        float4 acc = make_float4(0.f, 0.f, 0.f, 0.f);
        #pragma unroll 4
        for (int l = wave; l < len; l += 4) {
            const float4 v = *reinterpret_cast<const float4*>(
                basep + (size_t)ids[l] * D_);
            acc.x += v.x; acc.y += v.y; acc.z += v.z; acc.w += v.w;
        }
        *reinterpret_cast<float4*>(&ldsL[wave][lane * 4]) = acc;
    }
    __syncthreads();

    // cross-wave reduce, column = tid (fixed order -> deterministic)
    const float t  = ((ldsT[0][tid] + ldsT[1][tid]) + (ldsT[2][tid] + ldsT[3][tid]));
    const float lv = ((ldsL[0][tid] + ldsL[1][tid]) + (ldsL[2][tid] + ldsL[3][tid]));
    text_out [(size_t)n * D_ + tid] = t / (float)text_len[n];
    label_out[(size_t)n * D_ + tid] = lv;
}

// ---------------- Kernel B: batched projection, 8 nodes per block reuse Wg ----------------
__global__ __launch_bounds__(256) void proj_kernel(
    const float* __restrict__ text_out,   // [NN, D]
    const float* __restrict__ label_out,  // [NN, D]
    const float* __restrict__ Wg_text,
    const float* __restrict__ Wg_label,
    const float* __restrict__ w_adap,
    float*       __restrict__ h_comb)     // [NN, D] (may alias text_out)
{
    __shared__ float ldsT[NPB][D_];
    __shared__ float ldsL[NPB][D_];

    const int tid  = threadIdx.x;
    const int base_node = blockIdx.x * NPB;

    // stage x into LDS (coalesced float4 copy)
    const float4* __restrict__ gt = reinterpret_cast<const float4*>(
        text_out + (size_t)base_node * D_);
    const float4* __restrict__ gl = reinterpret_cast<const float4*>(
        label_out + (size_t)base_node * D_);
    float4* st = reinterpret_cast<float4*>(&ldsT[0][0]);
    float4* sl = reinterpret_cast<float4*>(&ldsL[0][0]);
    #pragma unroll
    for (int idx = tid; idx < NPB * D_ / 4; idx += 256) {
        st[idx] = gt[idx];
        sl[idx] = gl[idx];
    }
    __syncthreads();

    const int j = tid;   // output column
    float accT[NPB], accL[NPB];
    #pragma unroll
    for (int nd = 0; nd < NPB; ++nd) { accT[nd] = 0.f; accL[nd] = 0.f; }

    for (int d4 = 0; d4 < D_; d4 += 4) {
        const float wt0 = Wg_text[(size_t)(d4+0)*D_ + j];
        const float wt1 = Wg_text[(size_t)(d4+1)*D_ + j];
        const float wt2 = Wg_text[(size_t)(d4+2)*D_ + j];
        const float wt3 = Wg_text[(size_t)(d4+3)*D_ + j];
        const float wl0 = Wg_label[(size_t)(d4+0)*D_ + j];
        const float wl1 = Wg_label[(size_t)(d4+1)*D_ + j];
        const float wl2 = Wg_label[(size_t)(d4+2)*D_ + j];
        const float wl3 = Wg_label[(size_t)(d4+3)*D_ + j];
        #pragma unroll
        for (int nd = 0; nd < NPB; ++nd) {
            const float4 t = *reinterpret_cast<const float4*>(&ldsT[nd][d4]);
            accT[nd] = fmaf(t.w, wt3, fmaf(t.z, wt2, fmaf(t.y, wt1, fmaf(t.x, wt0, accT[nd]))));
            const float4 lv = *reinterpret_cast<const float4*>(&ldsL[nd][d4]);
            accL[nd] = fmaf(lv.w, wl3, fmaf(lv.z, wl2, fmaf(lv.y, wl1, fmaf(lv.x, wl0, accL[nd]))));
        }
    }

    const float w0 = w_adap[0] * (1.0f / (float)NPG_);
    const float w1 = w_adap[1] * (1.0f / (float)NPG_);
    #pragma unroll
    for (int nd = 0; nd < NPB; ++nd) {
        const float ht = accT[nd] > 0.f ? accT[nd] : 0.f;
        const float hl = accL[nd] > 0.f ? accL[nd] : 0.f;
        h_comb[(size_t)(base_node + nd) * D_ + j] = w0 * ht + w1 * hl;
    }
}

// ---------------- Kernel C: per-graph readout + MLP, 4 blocks per graph split Wout ----------------
__global__ __launch_bounds__(256) void graph_kernel(
    const float* __restrict__ h_comb,   // [NN, D]
    const float* __restrict__ W1,       // [D, D]
    const float* __restrict__ b1,       // [D]
    const float* __restrict__ Wout,     // [D, OUT]
    const float* __restrict__ bout,     // [OUT]
    float*       __restrict__ out)      // [BG, OUT]
{
    __shared__ float fused[D_];
    __shared__ float hrow[D_];

    const int bx   = blockIdx.x;
    const int b    = bx >> 2;
    const int part = bx & 3;
    const int tid  = threadIdx.x;

    // segment sum over the 64 nodes of this graph (scaling already applied)
    float acc = 0.f;
    const float* __restrict__ basep = h_comb + (size_t)b * NPG_ * D_ + tid;
    #pragma unroll 8
    for (int n = 0; n < NPG_; ++n) acc += basep[(size_t)n * D_];
    fused[tid] = acc;
    __syncthreads();

    // h = relu(fused @ W1 + b1)   (redundant across the 4 sibling blocks; cheap)
    float a1 = b1[tid];
    for (int d = 0; d < D_; ++d)
        a1 = fmaf(fused[d], W1[(size_t)d * D_ + tid], a1);
    hrow[tid] = a1 > 0.f ? a1 : 0.f;
    __syncthreads();

    // out column j = part*256 + tid
    const int j = part * 256 + tid;
    float o = bout[j];
    for (int d = 0; d < D_; ++d)
        o = fmaf(hrow[d], Wout[(size_t)d * OUT_ + j], o);
    out[(size_t)b * OUT_ + j] = o;
}

extern "C" void kernel_launch(void* const* d_in, const int* in_sizes, int n_in,
                              void* d_out, int out_size, void* d_ws, size_t ws_size,
                              hipStream_t stream) {
    const int*   text_ids  = (const int*)  d_in[0];
    const int*   label_ids = (const int*)  d_in[1];
    const int*   text_len  = (const int*)  d_in[2];
    const int*   label_len = (const int*)  d_in[3];
    const float* word_emb  = (const float*)d_in[4];
    const float* label_emb = (const float*)d_in[5];
    const float* Wg_text   = (const float*)d_in[6];
    const float* Wg_label  = (const float*)d_in[7];
    const float* w_adap    = (const float*)d_in[8];
    const float* W1        = (const float*)d_in[9];
    const float* b1        = (const float*)d_in[10];
    const float* Wout      = (const float*)d_in[11];
    const float* bout      = (const float*)d_in[12];

    // ws layout: [0, 4MB) text_out (reused as h_comb), [4MB, 8MB) label_out
    float* text_out  = (float*)d_ws;
    float* label_out = text_out + (size_t)NN * D_;
    float* h_comb    = text_out;          // alias: proj reads via LDS before writing
    float* out       = (float*)d_out;

    gather_kernel<<<NN, 256, 0, stream>>>(
        text_ids, label_ids, text_len, label_len,
        word_emb, label_emb, text_out, label_out);

    proj_kernel<<<NN / NPB, 256, 0, stream>>>(
        text_out, label_out, Wg_text, Wg_label, w_adap, h_comb);

    graph_kernel<<<BG * 4, 256, 0, stream>>>(
        h_comb, W1, b1, Wout, bout, out);
}